// Round 2
// baseline (111.260 us; speedup 1.0000x reference)
//
#include <hip/hip_runtime.h>
#include <math.h>

// Problem constants (static shapes from the reference)
#define B_   16
#define TT   1024
#define D_   512
#define TMEL 2049
#define TM   16      // frames per tile
#define KB   32      // tokens per LDS weight chunk
#define NTILE ((TMEL + TM - 1) / TM)   // 129

// One fused kernel: per (batch, 16-frame tile) block.
//  phase 0: block-scan duration -> centers c in LDS
//  phase 1: binary-search contributing-token window [ilo, ihi)
//  phase 2: windowed softmax stats (max + denom) per frame
//  phase 3: windowed weighted sum of encoder rows
// Zero d_ws usage -> nothing outside d_out is ever written.
__global__ __launch_bounds__(256) void expand_fused(const float* __restrict__ enc,
                                                    const float* __restrict__ dur,
                                                    float* __restrict__ out) {
    const int b    = blockIdx.y;
    const int tile = blockIdx.x;
    const int m0   = tile * TM;
    const int t    = threadIdx.x;
    const int lane = t & 63;
    const int wid  = t >> 6;

    __shared__ float s_c[TT];            // 4 KB centers
    __shared__ float s_wsum[4];
    __shared__ float s_red[256];         // 1 KB reduction scratch
    __shared__ float s_fmax[TM], s_finv[TM];
    __shared__ float s_w[KB * TM];       // 2 KB weight chunk

    // ---------- phase 0: cumsum(duration) -> centers ----------
    float4 v = ((const float4*)(dur + (size_t)b * TT))[t];   // 4 elems/thread
    float l0 = v.x;
    float l1 = l0 + v.y;
    float l2 = l1 + v.z;
    float l3 = l2 + v.w;
    float x = l3;                       // thread-local sum
    #pragma unroll
    for (int off = 1; off < 64; off <<= 1) {
        float y = __shfl_up(x, off);
        if (lane >= off) x += y;
    }
    if (lane == 63) s_wsum[wid] = x;
    __syncthreads();
    float w0 = s_wsum[0], w1 = s_wsum[1], w2 = s_wsum[2], w3 = s_wsum[3];
    float tot  = w0 + w1 + w2 + w3;
    float wpre = (wid > 0 ? w0 : 0.f) + (wid > 1 ? w1 : 0.f) + (wid > 2 ? w2 : 0.f);
    float excl = wpre + (x - l3);       // exclusive prefix of this thread's 4 elems
    float h = 0.5f * roundf(tot);       // 0.5 * t_tot
    s_c[4*t+0] = excl + l0 - h;
    s_c[4*t+1] = excl + l1 - h;
    s_c[4*t+2] = excl + l2 - h;
    s_c[4*t+3] = excl + l3 - h;
    __syncthreads();

    // ---------- phase 1: window via binary search (all threads, redundant) ----------
    const int m1c = min(m0 + TM - 1, TMEL - 1);
    const float lo = (float)m0 - 16.f;
    const float hi = (float)m1c + 16.f;
    int a, z, mid;
    a = 0; z = TT; while (a < z) { mid = (a + z) >> 1; if (s_c[mid] <  lo) a = mid + 1; else z = mid; } const int j0  = a;
    a = 0; z = TT; while (a < z) { mid = (a + z) >> 1; if (s_c[mid] <= hi) a = mid + 1; else z = mid; } const int j1  = a;
    a = 0; z = TT; while (a < z) { mid = (a + z) >> 1; if (s_c[mid] < (float)m0)  a = mid + 1; else z = mid; } const int jc0 = a;
    a = 0; z = TT; while (a < z) { mid = (a + z) >> 1; if (s_c[mid] < (float)m1c) a = mid + 1; else z = mid; } const int jc1 = a;
    int ilo = min(j0, jc0 - 8);  if (ilo < 0)  ilo = 0;
    int ihi = max(j1, jc1 + 9);  if (ihi > TT) ihi = TT;
    // window is provably non-empty (anchor span always intersects [0,TT))

    // ---------- phase 2: windowed softmax stats ----------
    const int f  = t & 15;              // frame within tile
    const int sl = t >> 4;              // slice 0..15
    const int mmf = min(m0 + f, TMEL - 1);
    const float fm = (float)mmf;
    float lmax = -3.4e38f;
    for (int i = ilo + sl; i < ihi; i += 16) {
        float d = fm - s_c[i];
        lmax = fmaxf(lmax, -0.1f * d * d);
    }
    s_red[t] = lmax;
    __syncthreads();
    #pragma unroll
    for (int st = 128; st >= 16; st >>= 1) {
        if (t < st) s_red[t] = fmaxf(s_red[t], s_red[t + st]);
        __syncthreads();
    }
    if (t < TM) s_fmax[t] = s_red[t];
    __syncthreads();
    const float myfmax = s_fmax[f];
    float lsum = 0.f;
    for (int i = ilo + sl; i < ihi; i += 16) {
        float d = fm - s_c[i];
        lsum += __expf(-0.1f * d * d - myfmax);
    }
    s_red[t] = lsum;
    __syncthreads();
    #pragma unroll
    for (int st = 128; st >= 16; st >>= 1) {
        if (t < st) s_red[t] += s_red[t + st];
        __syncthreads();
    }
    if (t < TM) s_finv[t] = 1.f / s_red[t];
    __syncthreads();

    // ---------- phase 3: windowed weighted sum ----------
    const int d0 = t * 2;               // each thread owns 2 consecutive d-columns
    float ax[TM], ay[TM];
    #pragma unroll
    for (int m = 0; m < TM; ++m) { ax[m] = 0.f; ay[m] = 0.f; }
    const float* encb = enc + (size_t)b * TT * D_;

    for (int k0 = ilo; k0 < ihi; k0 += KB) {
        const int kn = min(KB, ihi - k0);
        __syncthreads();                // protect s_w from previous chunk's readers
        for (int p = t; p < KB * TM; p += 256) {
            const int il = p >> 4;      // token within chunk
            const int fr = p & 15;      // frame within tile
            float wv = 0.f;
            if (il < kn) {
                const int mf = min(m0 + fr, TMEL - 1);
                float d = (float)mf - s_c[k0 + il];
                wv = __expf(-0.1f * d * d - s_fmax[fr]) * s_finv[fr];
            }
            s_w[p] = wv;
        }
        __syncthreads();
        for (int il = 0; il < kn; ++il) {
            const float2 ev = *(const float2*)(encb + (size_t)(k0 + il) * D_ + d0);
            const float4* swv = (const float4*)(s_w + il * TM);  // ds_read_b128 x4
            #pragma unroll
            for (int q = 0; q < 4; ++q) {
                const float4 wq = swv[q];
                ax[q*4+0] += wq.x * ev.x;  ay[q*4+0] += wq.x * ev.y;
                ax[q*4+1] += wq.y * ev.x;  ay[q*4+1] += wq.y * ev.y;
                ax[q*4+2] += wq.z * ev.x;  ay[q*4+2] += wq.z * ev.y;
                ax[q*4+3] += wq.w * ev.x;  ay[q*4+3] += wq.w * ev.y;
            }
        }
    }

    #pragma unroll
    for (int m = 0; m < TM; ++m) {
        const int mm2 = m0 + m;
        if (mm2 < TMEL) {
            *(float2*)(out + ((size_t)b * TMEL + mm2) * D_ + d0) = make_float2(ax[m], ay[m]);
        }
    }
}

// ---------------------------------------------------------------------------
extern "C" void kernel_launch(void* const* d_in, const int* in_sizes, int n_in,
                              void* d_out, int out_size, void* d_ws, size_t ws_size,
                              hipStream_t stream) {
    const float* enc = (const float*)d_in[0];   // [B, TT, D]
    const float* dur = (const float*)d_in[1];   // [B, TT]
    float* out = (float*)d_out;                 // [B, TMEL, D]
    (void)d_ws; (void)ws_size;                  // deliberately unused

    dim3 grid(NTILE, B_);
    expand_fused<<<grid, 256, 0, stream>>>(enc, dur, out);
}

// Round 4
// 104.716 us; speedup vs baseline: 1.0625x; 1.0625x over previous
//
#include <hip/hip_runtime.h>
#include <math.h>

// Problem constants (static shapes from the reference)
#define B_   16
#define TT   1024
#define D_   512
#define TMEL 2049
#define TM   16      // frames per tile
#define KB   64      // tokens per LDS weight chunk
#define NTILE ((TMEL + TM - 1) / TM)   // 129

typedef float nfloat4 __attribute__((ext_vector_type(4)));  // native vec for nontemporal store

// One fused kernel: per (batch, 16-frame tile) block, 256 threads.
//  phase 0: block-scan duration -> centers c in LDS
//  phase 1: binary-search contributing-token window [ilo, ihi)
//  phase 2: windowed softmax stats (max + denom) per frame
//  phase 3: windowed weighted sum; 2 frame-groups x 128 d-threads,
//           4 cols (float4) x 8 frames per thread.
__global__ __launch_bounds__(256) void expand_fused(const float* __restrict__ enc,
                                                    const float* __restrict__ dur,
                                                    float* __restrict__ out) {
    const int b    = blockIdx.y;
    const int tile = blockIdx.x;
    const int m0   = tile * TM;
    const int t    = threadIdx.x;
    const int lane = t & 63;
    const int wid  = t >> 6;

    __shared__ float s_c[TT];            // 4 KB centers
    __shared__ float s_wsum[4];
    __shared__ float s_red[256];         // 1 KB reduction scratch
    __shared__ float s_fmax[TM], s_finv[TM];
    __shared__ float s_w[KB * TM];       // 4 KB weight chunk

    // ---------- phase 0: cumsum(duration) -> centers ----------
    float4 v = ((const float4*)(dur + (size_t)b * TT))[t];   // 4 elems/thread
    float l0 = v.x;
    float l1 = l0 + v.y;
    float l2 = l1 + v.z;
    float l3 = l2 + v.w;
    float x = l3;                       // thread-local sum
    #pragma unroll
    for (int off = 1; off < 64; off <<= 1) {
        float y = __shfl_up(x, off);
        if (lane >= off) x += y;
    }
    if (lane == 63) s_wsum[wid] = x;
    __syncthreads();
    float w0 = s_wsum[0], w1 = s_wsum[1], w2 = s_wsum[2], w3 = s_wsum[3];
    float tot  = w0 + w1 + w2 + w3;
    float wpre = (wid > 0 ? w0 : 0.f) + (wid > 1 ? w1 : 0.f) + (wid > 2 ? w2 : 0.f);
    float excl = wpre + (x - l3);       // exclusive prefix of this thread's 4 elems
    float h = 0.5f * roundf(tot);       // 0.5 * t_tot
    s_c[4*t+0] = excl + l0 - h;
    s_c[4*t+1] = excl + l1 - h;
    s_c[4*t+2] = excl + l2 - h;
    s_c[4*t+3] = excl + l3 - h;
    __syncthreads();

    // ---------- phase 1: window via binary search (all threads, redundant) ----------
    const int m1c = min(m0 + TM - 1, TMEL - 1);
    const float lo = (float)m0 - 16.f;
    const float hi = (float)m1c + 16.f;
    int a, z, mid;
    a = 0; z = TT; while (a < z) { mid = (a + z) >> 1; if (s_c[mid] <  lo) a = mid + 1; else z = mid; } const int j0  = a;
    a = 0; z = TT; while (a < z) { mid = (a + z) >> 1; if (s_c[mid] <= hi) a = mid + 1; else z = mid; } const int j1  = a;
    a = 0; z = TT; while (a < z) { mid = (a + z) >> 1; if (s_c[mid] < (float)m0)  a = mid + 1; else z = mid; } const int jc0 = a;
    a = 0; z = TT; while (a < z) { mid = (a + z) >> 1; if (s_c[mid] < (float)m1c) a = mid + 1; else z = mid; } const int jc1 = a;
    int ilo = min(j0, jc0 - 8);  if (ilo < 0)  ilo = 0;
    int ihi = max(j1, jc1 + 9);  if (ihi > TT) ihi = TT;

    // ---------- phase 2: windowed softmax stats ----------
    const int f  = t & 15;              // frame within tile
    const int sl = t >> 4;              // slice 0..15
    const int mmf = min(m0 + f, TMEL - 1);
    const float fm = (float)mmf;
    float lmax = -3.4e38f;
    for (int i = ilo + sl; i < ihi; i += 16) {
        float d = fm - s_c[i];
        lmax = fmaxf(lmax, -0.1f * d * d);
    }
    s_red[t] = lmax;
    __syncthreads();
    #pragma unroll
    for (int st = 128; st >= 16; st >>= 1) {
        if (t < st) s_red[t] = fmaxf(s_red[t], s_red[t + st]);
        __syncthreads();
    }
    if (t < TM) s_fmax[t] = s_red[t];
    __syncthreads();
    const float myfmax = s_fmax[f];
    float lsum = 0.f;
    for (int i = ilo + sl; i < ihi; i += 16) {
        float d = fm - s_c[i];
        lsum += __expf(-0.1f * d * d - myfmax);
    }
    s_red[t] = lsum;
    __syncthreads();
    #pragma unroll
    for (int st = 128; st >= 16; st >>= 1) {
        if (t < st) s_red[t] += s_red[t + st];
        __syncthreads();
    }
    if (t < TM) s_finv[t] = 1.f / s_red[t];
    __syncthreads();

    // ---------- phase 3: windowed weighted sum ----------
    // 2 frame-groups x 128 d-threads; each thread: 4 cols (float4) x 8 frames.
    const int fg = t >> 7;              // frame group 0..1
    const int dt = t & 127;             // d-thread
    const int d0 = dt * 4;
    const int frbase = fg * 8;
    float4 acc[8];
    #pragma unroll
    for (int j = 0; j < 8; ++j) acc[j] = make_float4(0.f, 0.f, 0.f, 0.f);
    const float* encb = enc + (size_t)b * TT * D_;

    for (int k0 = ilo; k0 < ihi; k0 += KB) {
        const int kn = min(KB, ihi - k0);
        __syncthreads();                // protect s_w from previous chunk's readers
        for (int p = t; p < kn * TM; p += 256) {
            const int il = p >> 4;      // token within chunk
            const int fr = p & 15;      // frame within tile
            const int mf = min(m0 + fr, TMEL - 1);
            float d = (float)mf - s_c[k0 + il];
            s_w[p] = __expf(-0.1f * d * d - s_fmax[fr]) * s_finv[fr];
        }
        __syncthreads();
        for (int il = 0; il < kn; ++il) {
            const float4 ev = *(const float4*)(encb + (size_t)(k0 + il) * D_ + d0);
            const float4 wa = *(const float4*)(s_w + il * TM + frbase);      // broadcast
            const float4 wb = *(const float4*)(s_w + il * TM + frbase + 4);  // broadcast
            acc[0].x += wa.x * ev.x; acc[0].y += wa.x * ev.y; acc[0].z += wa.x * ev.z; acc[0].w += wa.x * ev.w;
            acc[1].x += wa.y * ev.x; acc[1].y += wa.y * ev.y; acc[1].z += wa.y * ev.z; acc[1].w += wa.y * ev.w;
            acc[2].x += wa.z * ev.x; acc[2].y += wa.z * ev.y; acc[2].z += wa.z * ev.z; acc[2].w += wa.z * ev.w;
            acc[3].x += wa.w * ev.x; acc[3].y += wa.w * ev.y; acc[3].z += wa.w * ev.z; acc[3].w += wa.w * ev.w;
            acc[4].x += wb.x * ev.x; acc[4].y += wb.x * ev.y; acc[4].z += wb.x * ev.z; acc[4].w += wb.x * ev.w;
            acc[5].x += wb.y * ev.x; acc[5].y += wb.y * ev.y; acc[5].z += wb.y * ev.z; acc[5].w += wb.y * ev.w;
            acc[6].x += wb.z * ev.x; acc[6].y += wb.z * ev.y; acc[6].z += wb.z * ev.z; acc[6].w += wb.z * ev.w;
            acc[7].x += wb.w * ev.x; acc[7].y += wb.w * ev.y; acc[7].z += wb.w * ev.z; acc[7].w += wb.w * ev.w;
        }
    }

    #pragma unroll
    for (int j = 0; j < 8; ++j) {
        const int mm2 = m0 + frbase + j;
        if (mm2 < TMEL) {
            nfloat4* dst = (nfloat4*)(out + ((size_t)b * TMEL + mm2) * D_ + d0);
            nfloat4 av = { acc[j].x, acc[j].y, acc[j].z, acc[j].w };
            __builtin_nontemporal_store(av, dst);   // write-once, bypass L2 pollution
        }
    }
}

// ---------------------------------------------------------------------------
extern "C" void kernel_launch(void* const* d_in, const int* in_sizes, int n_in,
                              void* d_out, int out_size, void* d_ws, size_t ws_size,
                              hipStream_t stream) {
    const float* enc = (const float*)d_in[0];   // [B, TT, D]
    const float* dur = (const float*)d_in[1];   // [B, TT]
    float* out = (float*)d_out;                 // [B, TMEL, D]
    (void)d_ws; (void)ws_size;                  // deliberately unused

    dim3 grid(NTILE, B_);
    expand_fused<<<grid, 256, 0, stream>>>(enc, dur, out);
}

// Round 5
// 102.935 us; speedup vs baseline: 1.0809x; 1.0173x over previous
//
#include <hip/hip_runtime.h>
#include <math.h>

// Problem constants (static shapes from the reference)
#define B_   16
#define TT   1024
#define D_   512
#define TMEL 2049
#define TM   16      // frames per tile
#define KB   64      // tokens per LDS weight chunk
#define NTILE ((TMEL + TM - 1) / TM)   // 129

typedef float nfloat4 __attribute__((ext_vector_type(4)));  // native vec for nontemporal store

// One fused kernel: per (batch, 16-frame tile) block, 256 threads.
//  phase 0: block-scan duration -> centers c (regs + LDS)
//  phase 1: window [ilo,ihi) from REGISTER predicates + wave reductions (no binary search)
//  phase 2: windowed softmax stats via intra-wave shfl reductions (wave w owns frames 4w..4w+3)
//  phase 3: windowed weighted sum; 2 frame-groups x 128 d-threads, 4 cols x 8 frames each.
__global__ __launch_bounds__(256) void expand_fused(const float* __restrict__ enc,
                                                    const float* __restrict__ dur,
                                                    float* __restrict__ out) {
    const int b    = blockIdx.y;
    const int tile = blockIdx.x;
    const int m0   = tile * TM;
    const int t    = threadIdx.x;
    const int lane = t & 63;
    const int wid  = t >> 6;

    __shared__ float s_c[TT];            // 4 KB centers
    __shared__ float s_wsum[4];
    __shared__ int4  s_ij[4];            // per-wave window candidates
    __shared__ float s_fmax[TM], s_finv[TM];
    __shared__ float s_w[KB * TM];       // 4 KB weight chunk

    // ---------- phase 0: cumsum(duration) -> centers ----------
    float4 v = ((const float4*)(dur + (size_t)b * TT))[t];   // 4 elems/thread
    float l0 = v.x;
    float l1 = l0 + v.y;
    float l2 = l1 + v.z;
    float l3 = l2 + v.w;
    float x = l3;                       // thread-local sum
    #pragma unroll
    for (int off = 1; off < 64; off <<= 1) {
        float y = __shfl_up(x, off);
        if (lane >= off) x += y;
    }
    if (lane == 63) s_wsum[wid] = x;
    __syncthreads();
    float w0 = s_wsum[0], w1 = s_wsum[1], w2 = s_wsum[2], w3 = s_wsum[3];
    float tot  = w0 + w1 + w2 + w3;
    float wpre = (wid > 0 ? w0 : 0.f) + (wid > 1 ? w1 : 0.f) + (wid > 2 ? w2 : 0.f);
    float excl = wpre + (x - l3);       // exclusive prefix of this thread's 4 elems
    float h = 0.5f * roundf(tot);       // 0.5 * t_tot
    const float c0 = excl + l0 - h;     // this thread's 4 centers (ascending), kept in regs
    const float c1 = excl + l1 - h;
    const float c2 = excl + l2 - h;
    const float c3 = excl + l3 - h;
    s_c[4*t+0] = c0;
    s_c[4*t+1] = c1;
    s_c[4*t+2] = c2;
    s_c[4*t+3] = c3;

    // ---------- phase 1: window from register predicates ----------
    const int   m1c = min(m0 + TM - 1, TMEL - 1);
    const float lo  = (float)m0 - 16.f;
    const float hi  = (float)m1c + 16.f;
    const float fm0 = (float)m0;
    const float fm1 = (float)m1c;
    const int base = 4 * t;
    // first index with c >= lo (centers ascending within thread)
    int j0  = (c0 >= lo)  ? base : (c1 >= lo)  ? base+1 : (c2 >= lo)  ? base+2 : (c3 >= lo)  ? base+3 : TT;
    // last index with c <= hi
    int j1  = (c3 <= hi)  ? base+3 : (c2 <= hi) ? base+2 : (c1 <= hi) ? base+1 : (c0 <= hi) ? base : -1;
    // first index with c >= m0 / m1c (lower_bound anchors)
    int jc0 = (c0 >= fm0) ? base : (c1 >= fm0) ? base+1 : (c2 >= fm0) ? base+2 : (c3 >= fm0) ? base+3 : TT;
    int jc1 = (c0 >= fm1) ? base : (c1 >= fm1) ? base+1 : (c2 >= fm1) ? base+2 : (c3 >= fm1) ? base+3 : TT;
    #pragma unroll
    for (int off = 32; off; off >>= 1) {
        j0  = min(j0,  __shfl_xor(j0,  off));
        j1  = max(j1,  __shfl_xor(j1,  off));
        jc0 = min(jc0, __shfl_xor(jc0, off));
        jc1 = min(jc1, __shfl_xor(jc1, off));
    }
    if (lane == 0) s_ij[wid] = make_int4(j0, j1, jc0, jc1);
    __syncthreads();                    // covers s_c and s_ij
    int4 r0 = s_ij[0], r1 = s_ij[1], r2 = s_ij[2], r3 = s_ij[3];
    const int J0  = min(min(r0.x, r1.x), min(r2.x, r3.x));
    const int J1  = max(max(r0.y, r1.y), max(r2.y, r3.y)) + 1;  // first idx with c > hi
    const int JC0 = min(min(r0.z, r1.z), min(r2.z, r3.z));
    const int JC1 = min(min(r0.w, r1.w), min(r2.w, r3.w));
    int ilo = min(J0, JC0 - 8);  if (ilo < 0)  ilo = 0;
    int ihi = max(J1, JC1 + 9);  if (ihi > TT) ihi = TT;

    // ---------- phase 2: windowed softmax stats (intra-wave reductions) ----------
    // wave `wid` owns frames 4*wid .. 4*wid+3; 16 slice-lanes per frame.
    const int fiw = lane & 3;           // frame within wave group
    const int sl  = lane >> 2;          // slice 0..15
    const int f   = (wid << 2) | fiw;   // frame within tile
    const int mmf = min(m0 + f, TMEL - 1);
    const float fm = (float)mmf;
    float lmax = -3.4e38f;
    for (int i = ilo + sl; i < ihi; i += 16) {
        float d = fm - s_c[i];
        lmax = fmaxf(lmax, -0.1f * d * d);
    }
    #pragma unroll
    for (int off = 4; off < 64; off <<= 1) lmax = fmaxf(lmax, __shfl_xor(lmax, off));
    float lsum = 0.f;
    for (int i = ilo + sl; i < ihi; i += 16) {
        float d = fm - s_c[i];
        lsum += __expf(-0.1f * d * d - lmax);
    }
    #pragma unroll
    for (int off = 4; off < 64; off <<= 1) lsum += __shfl_xor(lsum, off);
    if (lane < 4) {                     // lane k holds frame (wid<<2)|k
        s_fmax[(wid << 2) | lane] = lmax;
        s_finv[(wid << 2) | lane] = 1.f / lsum;
    }
    __syncthreads();

    // ---------- phase 3: windowed weighted sum ----------
    // 2 frame-groups x 128 d-threads; each thread: 4 cols (float4) x 8 frames.
    const int fg = t >> 7;              // frame group 0..1
    const int dt = t & 127;             // d-thread
    const int d0 = dt * 4;
    const int frbase = fg * 8;
    float4 acc[8];
    #pragma unroll
    for (int j = 0; j < 8; ++j) acc[j] = make_float4(0.f, 0.f, 0.f, 0.f);
    const float* encb = enc + (size_t)b * TT * D_;

    for (int k0 = ilo; k0 < ihi; k0 += KB) {
        const int kn = min(KB, ihi - k0);
        for (int p = t; p < kn * TM; p += 256) {
            const int il = p >> 4;      // token within chunk
            const int fr = p & 15;      // frame within tile
            const int mf = min(m0 + fr, TMEL - 1);
            float d = (float)mf - s_c[k0 + il];
            s_w[p] = __expf(-0.1f * d * d - s_fmax[fr]) * s_finv[fr];
        }
        __syncthreads();
        for (int il = 0; il < kn; ++il) {
            const float4 ev = *(const float4*)(encb + (size_t)(k0 + il) * D_ + d0);
            const float4 wa = *(const float4*)(s_w + il * TM + frbase);      // broadcast
            const float4 wb = *(const float4*)(s_w + il * TM + frbase + 4);  // broadcast
            acc[0].x += wa.x * ev.x; acc[0].y += wa.x * ev.y; acc[0].z += wa.x * ev.z; acc[0].w += wa.x * ev.w;
            acc[1].x += wa.y * ev.x; acc[1].y += wa.y * ev.y; acc[1].z += wa.y * ev.z; acc[1].w += wa.y * ev.w;
            acc[2].x += wa.z * ev.x; acc[2].y += wa.z * ev.y; acc[2].z += wa.z * ev.z; acc[2].w += wa.z * ev.w;
            acc[3].x += wa.w * ev.x; acc[3].y += wa.w * ev.y; acc[3].z += wa.w * ev.z; acc[3].w += wa.w * ev.w;
            acc[4].x += wb.x * ev.x; acc[4].y += wb.x * ev.y; acc[4].z += wb.x * ev.z; acc[4].w += wb.x * ev.w;
            acc[5].x += wb.y * ev.x; acc[5].y += wb.y * ev.y; acc[5].z += wb.y * ev.z; acc[5].w += wb.y * ev.w;
            acc[6].x += wb.z * ev.x; acc[6].y += wb.z * ev.y; acc[6].z += wb.z * ev.z; acc[6].w += wb.z * ev.w;
            acc[7].x += wb.w * ev.x; acc[7].y += wb.w * ev.y; acc[7].z += wb.w * ev.z; acc[7].w += wb.w * ev.w;
        }
        if (k0 + KB < ihi) __syncthreads();   // protect s_w only if another chunk follows
    }

    #pragma unroll
    for (int j = 0; j < 8; ++j) {
        const int mm2 = m0 + frbase + j;
        if (mm2 < TMEL) {
            nfloat4* dst = (nfloat4*)(out + ((size_t)b * TMEL + mm2) * D_ + d0);
            nfloat4 av = { acc[j].x, acc[j].y, acc[j].z, acc[j].w };
            __builtin_nontemporal_store(av, dst);   // write-once, bypass L2 pollution
        }
    }
}

// ---------------------------------------------------------------------------
extern "C" void kernel_launch(void* const* d_in, const int* in_sizes, int n_in,
                              void* d_out, int out_size, void* d_ws, size_t ws_size,
                              hipStream_t stream) {
    const float* enc = (const float*)d_in[0];   // [B, TT, D]
    const float* dur = (const float*)d_in[1];   // [B, TT]
    float* out = (float*)d_out;                 // [B, TMEL, D]
    (void)d_ws; (void)ws_size;                  // deliberately unused

    dim3 grid(NTILE, B_);
    expand_fused<<<grid, 256, 0, stream>>>(enc, dur, out);
}